// Round 1
// baseline (725.538 us; speedup 1.0000x reference)
//
#include <hip/hip_runtime.h>

// DecoderBlock: h_t = tanh(x_t @ U + h_{t-1} @ V + b)
// BZ=256, SEQ=512, IN=HID=256. All fp32.
//
// Kernel 1 (xu_gemm): XU[m,j] = sum_i x[m,i]*U[i,j] + b[j], m = b*512+t,
//   written into d_out decoder region (identical layout to decoder_outputs).
// Kernel 2 (rnn_rec): one workgroup per batch row (recurrence is independent
//   per batch row!). V held in registers distributed across 512 threads
//   (wave w owns k-rows [32w,32w+32), lane owns 4 cols -> float4 v[32]).
//   h in LDS; per step: fmac phase -> LDS partial reduce -> tanh -> overwrite
//   XU row t in d_out with h_t (in-place, own rows only).

#define SEQn 512
#define HIDn 256

// ---------------------------------------------------------------------------
// GEMM: 128x128 tile, BK=16, 256 threads, 8x8 per thread (4+4 split rows/cols)
// ---------------------------------------------------------------------------
__global__ __launch_bounds__(256, 4)
void xu_gemm(const float* __restrict__ X, const float* __restrict__ U,
             const float* __restrict__ bias, float* __restrict__ out)
{
    __shared__ float As[16][132];  // [k][m], +4 pad
    __shared__ float Bs[16][132];  // [k][n], +4 pad

    const int tid = threadIdx.x;
    const int tx = tid & 15;        // col group
    const int ty = tid >> 4;        // row group
    const int m0 = blockIdx.x * 128;
    const int n0 = blockIdx.y * 128;

    float acc[8][8];
    #pragma unroll
    for (int i = 0; i < 8; i++)
        #pragma unroll
        for (int j = 0; j < 8; j++) acc[i][j] = 0.f;

    for (int k0 = 0; k0 < 256; k0 += 16) {
        // A tile: 128 rows x 16 k  (x rows m0..m0+127)
        #pragma unroll
        for (int i = 0; i < 2; i++) {
            int f  = tid + 256 * i;          // float4 index, 512 total
            int m  = f >> 2;                 // 4 float4 per row
            int ko = (f & 3) * 4;
            float4 a = *(const float4*)(X + (size_t)(m0 + m) * 256 + k0 + ko);
            As[ko + 0][m] = a.x;
            As[ko + 1][m] = a.y;
            As[ko + 2][m] = a.z;
            As[ko + 3][m] = a.w;
        }
        // B tile: 16 k x 128 cols (U rows k0..k0+15)
        #pragma unroll
        for (int i = 0; i < 2; i++) {
            int f  = tid + 256 * i;
            int k  = f >> 5;                 // 32 float4 per row
            int no = (f & 31) * 4;
            *(float4*)&Bs[k][no] =
                *(const float4*)(U + (size_t)(k0 + k) * 256 + n0 + no);
        }
        __syncthreads();
        #pragma unroll
        for (int kk = 0; kk < 16; kk++) {
            float4 a0 = *(const float4*)&As[kk][4 * ty];
            float4 a1 = *(const float4*)&As[kk][64 + 4 * ty];
            float4 b0 = *(const float4*)&Bs[kk][4 * tx];
            float4 b1 = *(const float4*)&Bs[kk][64 + 4 * tx];
            float av[8] = {a0.x, a0.y, a0.z, a0.w, a1.x, a1.y, a1.z, a1.w};
            float bv[8] = {b0.x, b0.y, b0.z, b0.w, b1.x, b1.y, b1.z, b1.w};
            #pragma unroll
            for (int i = 0; i < 8; i++)
                #pragma unroll
                for (int j = 0; j < 8; j++)
                    acc[i][j] = fmaf(av[i], bv[j], acc[i][j]);
        }
        __syncthreads();
    }

    // epilogue: + bias, store
    float4 bb0 = *(const float4*)(bias + n0 + 4 * tx);
    float4 bb1 = *(const float4*)(bias + n0 + 64 + 4 * tx);
    #pragma unroll
    for (int i = 0; i < 8; i++) {
        int m = m0 + ((i < 4) ? (4 * ty + i) : (64 + 4 * ty + (i - 4)));
        float4 c0 = make_float4(acc[i][0] + bb0.x, acc[i][1] + bb0.y,
                                acc[i][2] + bb0.z, acc[i][3] + bb0.w);
        float4 c1 = make_float4(acc[i][4] + bb1.x, acc[i][5] + bb1.y,
                                acc[i][6] + bb1.z, acc[i][7] + bb1.w);
        *(float4*)(out + (size_t)m * 256 + n0 + 4 * tx)      = c0;
        *(float4*)(out + (size_t)m * 256 + n0 + 64 + 4 * tx) = c1;
    }
}

// ---------------------------------------------------------------------------
// Recurrence: 1 workgroup per batch row, 512 threads (8 waves).
// ---------------------------------------------------------------------------
__global__ __launch_bounds__(512, 2)
void rnn_rec(const float* __restrict__ enc, const float* __restrict__ V,
             float* __restrict__ out)
{
    __shared__ float hbuf[HIDn];
    __shared__ float part[8][HIDn];

    const int tid = threadIdx.x;
    const int w   = tid >> 6;   // wave 0..7: owns k-rows [32w, 32w+32)
    const int l   = tid & 63;   // lane: owns cols 4l..4l+3
    const int b   = blockIdx.x;

    // V slab into registers: v[kk] = V[32w+kk][4l..4l+3]  (128 VGPRs)
    float4 v[32];
    #pragma unroll
    for (int kk = 0; kk < 32; kk++)
        v[kk] = *(const float4*)(V + (size_t)(32 * w + kk) * 256 + 4 * l);

    float* outEnc = out + (size_t)b * HIDn;
    float* outDec = out + (size_t)65536 + (size_t)b * SEQn * HIDn;

    // h0 = encoder row b; also pass encoder input through to output 0
    if (tid < HIDn) {
        float h0 = enc[(size_t)b * HIDn + tid];
        hbuf[tid]   = h0;
        outEnc[tid] = h0;
    }
    float xu_cur = 0.f;
    if (tid < HIDn) xu_cur = outDec[tid];   // XU row 0 (GEMM output)
    __syncthreads();

    for (int t = 0; t < SEQn; t++) {
        // prefetch next XU row (independent of this step's compute)
        float xu_next = 0.f;
        if (tid < HIDn && t + 1 < SEQn)
            xu_next = outDec[(size_t)(t + 1) * HIDn + tid];

        // partial[j] = sum_{k in wave's rows} h[k] * V[k][j], 4 cols per lane
        float4 acc = make_float4(0.f, 0.f, 0.f, 0.f);
        #pragma unroll
        for (int kq = 0; kq < 8; kq++) {
            float4 h4 = *(const float4*)&hbuf[32 * w + 4 * kq];
            float hh[4] = {h4.x, h4.y, h4.z, h4.w};
            #pragma unroll
            for (int c = 0; c < 4; c++) {
                float4 vv = v[4 * kq + c];
                acc.x = fmaf(hh[c], vv.x, acc.x);
                acc.y = fmaf(hh[c], vv.y, acc.y);
                acc.z = fmaf(hh[c], vv.z, acc.z);
                acc.w = fmaf(hh[c], vv.w, acc.w);
            }
        }
        *(float4*)&part[w][4 * l] = acc;
        __syncthreads();

        if (tid < HIDn) {
            float s = xu_cur;
            #pragma unroll
            for (int ww = 0; ww < 8; ww++) s += part[ww][tid];
            // tanh(s) = 1 - 2/(e^{2s}+1)  (safe at +-inf)
            float e = __expf(2.f * s);
            float h = 1.f - 2.f / (e + 1.f);
            hbuf[tid] = h;                       // reads all done pre-barrier
            outDec[(size_t)t * HIDn + tid] = h;  // overwrite consumed XU row
        }
        xu_cur = xu_next;
        __syncthreads();
    }
}

extern "C" void kernel_launch(void* const* d_in, const int* in_sizes, int n_in,
                              void* d_out, int out_size, void* d_ws, size_t ws_size,
                              hipStream_t stream) {
    const float* enc  = (const float*)d_in[0];   // [256,256]
    const float* x    = (const float*)d_in[1];   // [256,512,256]
    const float* U    = (const float*)d_in[2];   // [256,256]
    const float* V    = (const float*)d_in[3];   // [256,256]
    const float* bias = (const float*)d_in[4];   // [256]
    float* out = (float*)d_out;                  // 65536 + 33554432 floats

    float* outDec = out + 65536;

    // XU = x @ U + b  -> decoder region of d_out (same layout)
    dim3 ggrid(131072 / 128, 256 / 128);
    xu_gemm<<<ggrid, 256, 0, stream>>>(x, U, bias, outDec);

    // sequential recurrence, one workgroup per batch row
    rnn_rec<<<256, 512, 0, stream>>>(enc, V, out);
}

// Round 2
// 604.613 us; speedup vs baseline: 1.2000x; 1.2000x over previous
//
#include <hip/hip_runtime.h>
#include <hip/hip_bf16.h>

// DecoderBlock: h_t = tanh(x_t @ U + h_{t-1} @ V + b)
// BZ=256, SEQ=512, IN=HID=256. fp32 in/out.
//
// prep_B : U (fp32) -> bf16 B-fragment-ordered buffer (128 KB).
// xu_gemm: XU = x @ U + b via bf16 MFMA 16x16x32, LDS-free (A-frags converted
//          inline from fp32 global, B-frags from pre-packed bf16). Written to
//          the decoder region of d_out.
// rnn_rec: 1 WG per batch row, 512 thr. V in registers (float4 v[32]/thread);
//          h broadcast via v_readlane -> SGPR-operand FMAs (no LDS broadcast);
//          partials reduced through LDS; tanh; in-place overwrite of XU rows.

#define SEQn 512
#define HIDn 256

typedef __attribute__((ext_vector_type(4))) float  floatx4;
typedef __attribute__((ext_vector_type(8))) short  short8;

__device__ __forceinline__ short f2bf(float f) {
    __hip_bfloat16 h = __float2bfloat16(f);
    return *reinterpret_cast<short*>(&h);
}

// ---------------------------------------------------------------------------
// Pack U[k][n] -> wsB chunks: chunk idx = (kb*4 + q)*256 + n holds
// U[kb*32 + q*8 + j][n] (j=0..7) as bf16. 8192 chunks x 16 B = 128 KB.
// ---------------------------------------------------------------------------
__global__ void prep_B(const float* __restrict__ U, short* __restrict__ wsB) {
    int idx = blockIdx.x * 256 + threadIdx.x;   // 0..8191
    int n  = idx & 255;
    int q  = (idx >> 8) & 3;
    int kb = idx >> 10;
    int k0 = kb * 32 + q * 8;
    short8 c;
    #pragma unroll
    for (int j = 0; j < 8; j++)
        c[j] = f2bf(U[(size_t)(k0 + j) * 256 + n]);
    *(short8*)(wsB + (size_t)idx * 8) = c;
}

// ---------------------------------------------------------------------------
// MFMA GEMM: block tile 128 rows x 128 cols, 4 waves, wave w owns rows
// 32w..32w+32 (2 m-tiles) x all 128 cols (8 n-tiles). K-loop BK=32, 8 iters.
// A-frag: A[m=lane&15][k=quad*8+j]; B-frag: B[k=quad*8+j][n=lane&15];
// C/D: col=lane&15, row=quad*4+reg.
// ---------------------------------------------------------------------------
__global__ __launch_bounds__(256, 4)
void xu_gemm(const float* __restrict__ X, const short* __restrict__ wsB,
             const float* __restrict__ bias, float* __restrict__ out)
{
    const int tid = threadIdx.x;
    const int l   = tid & 63;
    const int w   = tid >> 6;          // wave 0..3
    const int lr  = l & 15;
    const int q   = l >> 4;
    const int m0  = blockIdx.y * 128;
    const int n0  = blockIdx.x * 128;

    floatx4 acc[2][8];
    #pragma unroll
    for (int mt = 0; mt < 2; mt++)
        #pragma unroll
        for (int nt = 0; nt < 8; nt++)
            acc[mt][nt] = (floatx4){0.f, 0.f, 0.f, 0.f};

    const size_t rowA = (size_t)(m0 + 32 * w + lr);

    for (int kb = 0; kb < 8; kb++) {
        short8 af[2];
        #pragma unroll
        for (int mt = 0; mt < 2; mt++) {
            const float* p = X + (rowA + 16 * mt) * 256 + kb * 32 + q * 8;
            float4 a0 = *(const float4*)p;
            float4 a1 = *(const float4*)(p + 4);
            af[mt][0] = f2bf(a0.x); af[mt][1] = f2bf(a0.y);
            af[mt][2] = f2bf(a0.z); af[mt][3] = f2bf(a0.w);
            af[mt][4] = f2bf(a1.x); af[mt][5] = f2bf(a1.y);
            af[mt][6] = f2bf(a1.z); af[mt][7] = f2bf(a1.w);
        }
        #pragma unroll
        for (int nt = 0; nt < 8; nt++) {
            short8 bfr = *(const short8*)(wsB +
                ((size_t)(kb * 4 + q) * 256 + n0 + 16 * nt + lr) * 8);
            acc[0][nt] = __builtin_amdgcn_mfma_f32_16x16x32_bf16(af[0], bfr, acc[0][nt], 0, 0, 0);
            acc[1][nt] = __builtin_amdgcn_mfma_f32_16x16x32_bf16(af[1], bfr, acc[1][nt], 0, 0, 0);
        }
    }

    #pragma unroll
    for (int nt = 0; nt < 8; nt++) {
        float bv = bias[n0 + 16 * nt + lr];
        #pragma unroll
        for (int mt = 0; mt < 2; mt++) {
            #pragma unroll
            for (int r = 0; r < 4; r++) {
                int row = m0 + 32 * w + 16 * mt + 4 * q + r;
                out[(size_t)row * 256 + n0 + 16 * nt + lr] = acc[mt][nt][r] + bv;
            }
        }
    }
}

// ---------------------------------------------------------------------------
// Recurrence: 1 workgroup per batch row, 512 threads (8 waves).
// wave w owns k-rows [32w,32w+32); lane owns cols 4l..4l+3.
// h broadcast: one ds_read_b32/wave + v_readlane -> SGPR-src FMAs.
// ---------------------------------------------------------------------------
__global__ __launch_bounds__(512, 2)
void rnn_rec(const float* __restrict__ enc, const float* __restrict__ V,
             float* __restrict__ out)
{
    __shared__ float hbuf[HIDn];
    __shared__ float part[8][HIDn];

    const int tid = threadIdx.x;
    const int w   = tid >> 6;
    const int l   = tid & 63;
    const int b   = blockIdx.x;

    float4 v[32];
    #pragma unroll
    for (int kk = 0; kk < 32; kk++)
        v[kk] = *(const float4*)(V + (size_t)(32 * w + kk) * 256 + 4 * l);

    float* outEnc = out + (size_t)b * HIDn;
    float* outDec = out + (size_t)65536 + (size_t)b * SEQn * HIDn;

    if (tid < HIDn) {
        float h0 = enc[(size_t)b * HIDn + tid];
        hbuf[tid]   = h0;
        outEnc[tid] = h0;
    }
    float xu_cur = 0.f;
    if (tid < HIDn) xu_cur = outDec[tid];
    __syncthreads();

    for (int t = 0; t < SEQn; t++) {
        float xu_next = 0.f;
        if (tid < HIDn && t + 1 < SEQn)
            xu_next = outDec[(size_t)(t + 1) * HIDn + tid];

        // wave-uniform h slice: lane kk holds h[32w+kk] (lanes 32-63 dup)
        float hv = hbuf[32 * w + (l & 31)];
        int   hvi = __builtin_bit_cast(int, hv);

        float4 acc = make_float4(0.f, 0.f, 0.f, 0.f);
        #pragma unroll
        for (int kk = 0; kk < 32; kk++) {
            float hs = __builtin_bit_cast(float, __builtin_amdgcn_readlane(hvi, kk));
            float4 vv = v[kk];
            acc.x = fmaf(hs, vv.x, acc.x);
            acc.y = fmaf(hs, vv.y, acc.y);
            acc.z = fmaf(hs, vv.z, acc.z);
            acc.w = fmaf(hs, vv.w, acc.w);
        }
        *(float4*)&part[w][4 * l] = acc;
        __syncthreads();

        if (tid < HIDn) {
            float s = xu_cur;
            #pragma unroll
            for (int ww = 0; ww < 8; ww++) s += part[ww][tid];
            float e = __expf(2.f * s);
            float h = 1.f - 2.f / (e + 1.f);
            hbuf[tid] = h;
            outDec[(size_t)t * HIDn + tid] = h;
        }
        xu_cur = xu_next;
        __syncthreads();
    }
}

extern "C" void kernel_launch(void* const* d_in, const int* in_sizes, int n_in,
                              void* d_out, int out_size, void* d_ws, size_t ws_size,
                              hipStream_t stream) {
    const float* enc  = (const float*)d_in[0];   // [256,256]
    const float* x    = (const float*)d_in[1];   // [256,512,256]
    const float* U    = (const float*)d_in[2];   // [256,256]
    const float* V    = (const float*)d_in[3];   // [256,256]
    const float* bias = (const float*)d_in[4];   // [256]
    float* out = (float*)d_out;                  // 65536 + 33554432 floats

    float* outDec = out + 65536;

    // bf16 B-frag scratch (128 KB): d_ws, or the 256 KB encoder-output region
    // of d_out as fallback (rnn_rec overwrites it only after xu_gemm is done).
    short* wsB = (ws_size >= 131072) ? (short*)d_ws : (short*)out;

    prep_B<<<32, 256, 0, stream>>>(U, wsB);

    dim3 ggrid(2, 1024);   // (n-blocks, m-blocks)
    xu_gemm<<<ggrid, 256, 0, stream>>>(x, wsB, bias, outDec);

    rnn_rec<<<256, 512, 0, stream>>>(enc, V, out);
}